// Round 5
// baseline (282.137 us; speedup 1.0000x reference)
//
#include <hip/hip_runtime.h>

// GaborLayer: out[p][o] = sin(x[p]·W[o] + b[o]) * exp(-0.5*gamma[o]*||x[p]-mu[o]||^2)
// P = 262144 points, OUT = 256, IN = 3. Output = 256 MiB fp32 -> write-BW bound.
//
// R6 = R5 resubmitted verbatim (R5's bench was an infra failure: "MI355X
// container failed twice" -- no compile/correctness signal, kernel never ran).
//
// In-flight store DEPTH experiment. Ledger: store type (R2, -7.7 confounded),
// occupancy 4->8 (R3, -2), spatial interleave (R4, +6.4 REGRESSION -> reverted).
// All prior variants held per-wave outstanding stores at 2-4 (compiler waits
// vmcnt before reusing the result quad), so per-SIMD in-flight bytes were ~16 KiB
// in BOTH R2 (4w x 4 stores) and R3 (8w x 2 stores) -- the occupancy null is
// explained by accidentally-constant depth. The 6.4 TB/s fill kernel never reuses
// its data register -> up to 63 outstanding stores/wave. Little's law at us-scale
// write-queue latency needs ~13 MB chip-wide in flight; we had ~16 MB nominal.
//   - 8-point trips, 8 DISTINCT v4f result quads: compute all 8, burst 8 stores.
//     Each wave keeps 8 KiB outstanding through the next trip's ~540-cyc compute.
//   - __launch_bounds__(256,6): ~84 VGPR budget (36 consts + 32 results + temps),
//     6 waves/SIMD -> 48 KiB/SIMD in flight, 3x every prior variant.
//   - Contiguous per-wave chunks (R4's interleave reverted).
//   - x prefetched one trip ahead into SGPRs (wave-uniform s_load, lgkmcnt
//     covered by the 540-cyc compute phase).
// Kept: plain dwordx4 stores, constants pre-folded into v_sin (revolutions) /
// v_exp (log2) domain.

#define OUT_F 256

typedef float v4f __attribute__((ext_vector_type(4)));

__global__ __launch_bounds__(256, 6) void gabor_kernel(
    const float* __restrict__ x,      // (P, 3)
    const float* __restrict__ W,      // (256, 3)
    const float* __restrict__ b,      // (256,)
    const float* __restrict__ mu,     // (256, 3)
    const float* __restrict__ gamma,  // (256,)
    float* __restrict__ out,          // (P, 256)
    int P)
{
    const int lane        = threadIdx.x & 63;
    const int waveInBlock = threadIdx.x >> 6;
    const int wavesPerBlk = blockDim.x >> 6;
    const int wavesTotal  = gridDim.x * wavesPerBlk;
    // Force wave-uniformity so x addressing is scalar (s_load, lgkmcnt).
    const int waveId = __builtin_amdgcn_readfirstlane(blockIdx.x * wavesPerBlk + waveInBlock);

    const int o = lane << 2;  // 4 consecutive out-features per lane

    constexpr float INV_2PI = 0.15915493667125702f;  // 1/(2*pi)
    constexpr float LOG2E   = 1.4426950408889634f;   // log2(e)

    // Per-feature constants, pre-folded (36 VGPRs, live whole kernel):
    //   lin_rev = wr·x + brv            (revolutions; feeds v_sin directly)
    //   ea      = aj*||x||^2 + n·x + dj (log2 units; feeds v_exp directly)
    float wr0[4], wr1[4], wr2[4], brv[4];
    float n0[4], n1[4], n2[4], dj[4], aj[4];
#pragma unroll
    for (int j = 0; j < 4; ++j) {
        const int oj = o + j;
        const float g2  = -0.5f * LOG2E * gamma[oj];
        const float m0v = mu[oj * 3 + 0];
        const float m1v = mu[oj * 3 + 1];
        const float m2v = mu[oj * 3 + 2];
        wr0[j] = W[oj * 3 + 0] * INV_2PI;
        wr1[j] = W[oj * 3 + 1] * INV_2PI;
        wr2[j] = W[oj * 3 + 2] * INV_2PI;
        brv[j] = b[oj] * INV_2PI;
        aj[j]  = g2;
        n0[j]  = -2.0f * g2 * m0v;
        n1[j]  = -2.0f * g2 * m1v;
        n2[j]  = -2.0f * g2 * m2v;
        dj[j]  = g2 * (m0v * m0v + m1v * m1v + m2v * m2v);
    }

    // Contiguous chunk of points per wave (x reads walk forward -> s_load merge).
    const int ppw  = (P + wavesTotal - 1) / wavesTotal;   // 32 at P=262144
    const int p0   = waveId * ppw;
    const int pend = (p0 + ppw < P) ? (p0 + ppw) : P;

    int p = p0;
    if (p + 8 <= pend) {
        // Prologue: 24 wave-uniform scalar loads (8 points of x) -> SGPRs.
        float xv[24];
        {
            const float* xp = x + (size_t)p * 3;
#pragma unroll
            for (int i = 0; i < 24; ++i) xv[i] = xp[i];
        }

        while (p + 8 <= pend) {
            const int pn = p + 8;
            // Prefetch next trip's x now; lgkmcnt wait lands after ~540 cyc of
            // compute, fully covered. Clamp keeps the read in-bounds.
            const int pf = (pn + 8 <= P) ? pn : (P - 8);
            float xn[24];
            {
                const float* xq = x + (size_t)pf * 3;
#pragma unroll
                for (int i = 0; i < 24; ++i) xn[i] = xq[i];
            }

            // Compute ALL 8 result quads first (32 VGPRs live), THEN burst the
            // 8 stores. Distinct registers per point -> no vmcnt wait until the
            // next trip's compute overwrites r[0]; 8 KiB/wave stays in flight.
            v4f r[8];
#pragma unroll
            for (int q = 0; q < 8; ++q) {
                const float x0 = xv[q * 3 + 0];
                const float x1 = xv[q * 3 + 1];
                const float x2 = xv[q * 3 + 2];
                const float xs = x0 * x0 + x1 * x1 + x2 * x2;
#pragma unroll
                for (int j = 0; j < 4; ++j) {
                    const float lin = fmaf(wr0[j], x0, fmaf(wr1[j], x1, fmaf(wr2[j], x2, brv[j])));
                    const float t   = fmaf(n0[j], x0, fmaf(n1[j], x1, fmaf(n2[j], x2, dj[j])));
                    const float ea  = fmaf(aj[j], xs, t);
                    r[q][j] = __builtin_amdgcn_sinf(lin) * __builtin_amdgcn_exp2f(ea);
                }
            }

            float* orow = out + (size_t)p * OUT_F + o;
#pragma unroll
            for (int q = 0; q < 8; ++q) {
                // 64 lanes x 16B = contiguous 1 KiB row per store; 8 rows = 8 KiB
                // contiguous per wave-trip.
                *reinterpret_cast<v4f*>(orow + (size_t)q * OUT_F) = r[q];
            }

            p = pn;
#pragma unroll
            for (int i = 0; i < 24; ++i) xv[i] = xn[i];
        }
    }

    // Tail (P divides evenly in practice; kept for safety).
    for (; p < pend; ++p) {
        const float x0 = x[p * 3 + 0];
        const float x1 = x[p * 3 + 1];
        const float x2 = x[p * 3 + 2];
        const float xs = x0 * x0 + x1 * x1 + x2 * x2;
        v4f r;
#pragma unroll
        for (int j = 0; j < 4; ++j) {
            const float lin = fmaf(wr0[j], x0, fmaf(wr1[j], x1, fmaf(wr2[j], x2, brv[j])));
            const float t   = fmaf(n0[j], x0, fmaf(n1[j], x1, fmaf(n2[j], x2, dj[j])));
            const float ea  = fmaf(aj[j], xs, t);
            r[j] = __builtin_amdgcn_sinf(lin) * __builtin_amdgcn_exp2f(ea);
        }
        *reinterpret_cast<v4f*>(out + (size_t)p * OUT_F + o) = r;
    }
}

extern "C" void kernel_launch(void* const* d_in, const int* in_sizes, int n_in,
                              void* d_out, int out_size, void* d_ws, size_t ws_size,
                              hipStream_t stream) {
    const float* x     = (const float*)d_in[0];
    const float* W     = (const float*)d_in[1];
    const float* b     = (const float*)d_in[2];
    const float* mu    = (const float*)d_in[3];
    const float* gamma = (const float*)d_in[4];
    float* out = (float*)d_out;

    const int P = in_sizes[0] / 3;  // B*N points

    // 2048 blocks x 4 waves = 8192 waves; 32 contiguous points per wave,
    // processed as 4 trips of 8 points (8 KiB stored per trip).
    gabor_kernel<<<2048, 256, 0, stream>>>(x, W, b, mu, gamma, out, P);
}